// Round 1
// baseline (231.727 us; speedup 1.0000x reference)
//
#include <hip/hip_runtime.h>
#include <hip/hip_bf16.h>
#include <math.h>

// NoisyTopkRouter round 7: occupancy push.
// Theory: r6 was latency-bound at 19.5% occupancy (grid 512 = 2 blocks/CU,
// MfmaUtil 12%, VALUBusy 21%, HBM 13% -- nothing saturated).
// - M_TILE 64 -> 32: grid 1024 -> 4 blocks/CU (16 waves/CU), __launch_bounds__(256,4).
// - K_STAGE 64 per barrier (2 MFMA k-chunks): 16 barriers instead of 32.
//   Per-thread staging is still exactly 8 floats/stage (same cvt8 pipeline).
// - B loads moved in-stage (no cross-stage reg prefetch) + raw-A depth 2,
//   to keep VGPR <= 128 so the 4-blocks/CU occupancy actually materializes.
// Numerics identical to r6: bf16 hi/lo split, 3-term MFMA products.

#define T_TOKENS 32768
#define D_MODEL  1024
#define NE       64
#define NCOL     128
#define M_TILE   32
#define KSTAGE   64
#define NSTAGE   16
#define CS_LD    68
#define OUT_IDX_BASE ((size_t)T_TOKENS * NE)
#define W_ELEMS  (NCOL * D_MODEL)

typedef short  bf16x8  __attribute__((ext_vector_type(8)));
typedef float  floatx4 __attribute__((ext_vector_type(4)));

__device__ __forceinline__ float softplus_f(float x) {
    return fmaxf(x, 0.f) + log1pf(expf(-fabsf(x)));
}

// 8 floats -> packed bf16 hi (int4) + bf16 lo (int4). RNE hi, exact residual,
// RNE lo — numerically identical to rounds 2-6.
__device__ __forceinline__ void cvt8(const float4 a, const float4 b,
                                     int4* hi, int4* lo) {
    float v[8] = {a.x, a.y, a.z, a.w, b.x, b.y, b.z, b.w};
    int hw[4], lw[4];
    #pragma unroll
    for (int p = 0; p < 4; ++p) {
        float2 f2 = make_float2(v[2 * p], v[2 * p + 1]);
        __hip_bfloat162 h2 = __float22bfloat162_rn(f2);
        int u; __builtin_memcpy(&u, &h2, 4);
        float h0 = __uint_as_float(((unsigned)u) << 16);
        float h1 = __uint_as_float(((unsigned)u) & 0xFFFF0000u);
        float2 l2 = make_float2(v[2 * p] - h0, v[2 * p + 1] - h1);
        __hip_bfloat162 L2 = __float22bfloat162_rn(l2);
        int ul; __builtin_memcpy(&ul, &L2, 4);
        hw[p] = u; lw[p] = ul;
    }
    *hi = make_int4(hw[0], hw[1], hw[2], hw[3]);
    *lo = make_int4(lw[0], lw[1], lw[2], lw[3]);
}

// ---------------- prepack: W -> hi/lo bf16 in B-frag order ----------------
// elem index = ((ntile*128 + kgrp)*16 + n16)*8 + j ; value = W[ntile*16+n16][kgrp*8+j]
__global__ __launch_bounds__(256) void prepack_w(
    const float* __restrict__ Wr, const float* __restrict__ Wn,
    short* __restrict__ Bh, short* __restrict__ Bl)
{
    int g   = blockIdx.x * 256 + threadIdx.x;
    int n   = g & 15;
    int kg  = (g >> 4) & 127;
    int t2  = g >> 11;
    int col = t2 * 16 + n;
    const float* src = (col < NE ? Wr + (size_t)col * D_MODEL
                                 : Wn + (size_t)(col - NE) * D_MODEL) + kg * 8;
    float4 a = *(const float4*)src;
    float4 b = *(const float4*)(src + 4);
    int4 hi, lo;
    cvt8(a, b, &hi, &lo);
    *(int4*)(Bh + (size_t)g * 8) = hi;
    *(int4*)(Bl + (size_t)g * 8) = lo;
}

// ---------------- main fused kernel ----------------
__global__ __launch_bounds__(256, 4) void router_mfma(
    const float* __restrict__ A,
    const float* __restrict__ noise,
    const float* __restrict__ br,
    const float* __restrict__ bn,
    const short* __restrict__ Bh,
    const short* __restrict__ Bl,
    float* __restrict__ out)
{
    __shared__ __align__(16) short Ah[2][M_TILE * KSTAGE];
    __shared__ __align__(16) short Al[2][M_TILE * KSTAGE];
    __shared__ float Cs[M_TILE * CS_LD];
    __shared__ float s_p1[M_TILE], s_p2[M_TILE];
    __shared__ int   s_e1[M_TILE], s_e2[M_TILE];

    const int tid  = threadIdx.x;
    const int lane = tid & 63;
    const int wid  = tid >> 6;   // wave: route ntile wid, noise ntile wid+4
    const int n16  = lane & 15;
    const int quad = lane >> 4;
    const int m0   = blockIdx.x * M_TILE;

    // staging: row r = tid&31, k-slot kh = tid>>5 (0..7) -> k = kh*8..kh*8+7
    // covers 32 rows x 64 k = 2048 floats = 8 floats/thread per stage.
    const int r  = tid & 31;
    const int kh = tid >> 5;
    const float* pA = A + (size_t)(m0 + r) * D_MODEL + kh * 8;
    // frag-order elem base: chunk c = kh>>2, kgrp = kh&3 ->
    // ((c*4+kgrp)*M + row)*8 = (kh*M + r)*8, 16B aligned, wave-contiguous.
    const int sBase = (kh * M_TILE + r) * 8;

    const int bBaseR = ((wid * 128 + quad) * 16 + n16) * 8;
    const int bBaseN = (((4 + wid) * 128 + quad) * 16 + n16) * 8;

    floatx4 acc[2][2];   // [m-frag][route/noise]
    #pragma unroll
    for (int i = 0; i < 2; ++i) { acc[i][0] = (floatx4)0.f; acc[i][1] = (floatx4)0.f; }

    // ---- prologue: stage 0 into buf 0; raw A for stage 1 in regs ----
    {
        float4 a0 = *(const float4*)pA;
        float4 a1 = *(const float4*)(pA + 4);
        int4 hi, lo;
        cvt8(a0, a1, &hi, &lo);
        *(int4*)&Ah[0][sBase] = hi;
        *(int4*)&Al[0][sBase] = lo;
    }
    float4 aP1a = *(const float4*)(pA + KSTAGE);
    float4 aP1b = *(const float4*)(pA + KSTAGE + 4);
    __syncthreads();

    for (int s = 0; s < NSTAGE; ++s) {
        const int cur = s & 1, nxt = cur ^ 1;

        // raw A for stage s+2 (depth 2)
        float4 f0, f1;
        if (s + 2 < NSTAGE) {
            f0 = *(const float4*)(pA + (s + 2) * KSTAGE);
            f1 = *(const float4*)(pA + (s + 2) * KSTAGE + 4);
        }

        // B frags for both k-chunks of this stage (L2-resident; TLP hides latency)
        bf16x8 bh[2][2], bl[2][2];   // [chunk][route/noise]
        #pragma unroll
        for (int c = 0; c < 2; ++c) {
            const int o = (s * 2 + c) * 512;
            bh[c][0] = *(const bf16x8*)(Bh + bBaseR + o);
            bl[c][0] = *(const bf16x8*)(Bl + bBaseR + o);
            bh[c][1] = *(const bf16x8*)(Bh + bBaseN + o);
            bl[c][1] = *(const bf16x8*)(Bl + bBaseN + o);
        }

        // A frags (2 chunks x 2 m-frags; 16 consecutive lanes read 256B contiguous)
        bf16x8 afh[2][2], afl[2][2];
        #pragma unroll
        for (int c = 0; c < 2; ++c)
            #pragma unroll
            for (int mf = 0; mf < 2; ++mf) {
                int g = ((c * 4 + quad) * M_TILE + mf * 16 + n16) * 8;
                afh[c][mf] = *(const bf16x8*)&Ah[cur][g];
                afl[c][mf] = *(const bf16x8*)&Al[cur][g];
            }

        // convert + stage chunk s+1 (raw loaded last stage)
        if (s + 1 < NSTAGE) {
            int4 hi, lo;
            cvt8(aP1a, aP1b, &hi, &lo);
            *(int4*)&Ah[nxt][sBase] = hi;
            *(int4*)&Al[nxt][sBase] = lo;
        }

        // 24 MFMAs (4 independent acc chains)
        #pragma unroll
        for (int c = 0; c < 2; ++c)
            #pragma unroll
            for (int mf = 0; mf < 2; ++mf) {
                acc[mf][0] = __builtin_amdgcn_mfma_f32_16x16x32_bf16(afh[c][mf], bh[c][0], acc[mf][0], 0, 0, 0);
                acc[mf][0] = __builtin_amdgcn_mfma_f32_16x16x32_bf16(afh[c][mf], bl[c][0], acc[mf][0], 0, 0, 0);
                acc[mf][0] = __builtin_amdgcn_mfma_f32_16x16x32_bf16(afl[c][mf], bh[c][0], acc[mf][0], 0, 0, 0);
                acc[mf][1] = __builtin_amdgcn_mfma_f32_16x16x32_bf16(afh[c][mf], bh[c][1], acc[mf][1], 0, 0, 0);
                acc[mf][1] = __builtin_amdgcn_mfma_f32_16x16x32_bf16(afh[c][mf], bl[c][1], acc[mf][1], 0, 0, 0);
                acc[mf][1] = __builtin_amdgcn_mfma_f32_16x16x32_bf16(afl[c][mf], bh[c][1], acc[mf][1], 0, 0, 0);
            }

        __syncthreads();

        aP1a = f0; aP1b = f1;
    }

    // ---- lane-local fuse: noisy = route + noise * softplus(noise_logit) ----
    // D layout: col = lane&15 (expert within ntile), row = quad*4 + rr
    {
        int e = wid * 16 + n16;
        float brv = br[e], bnv = bn[e];
        #pragma unroll
        for (int mf = 0; mf < 2; ++mf)
            #pragma unroll
            for (int rr = 0; rr < 4; ++rr) {
                int t = mf * 16 + quad * 4 + rr;
                float nz    = noise[(size_t)(m0 + t) * NE + e];
                float route = acc[mf][0][rr] + brv;
                float nl    = acc[mf][1][rr] + bnv;
                Cs[t * CS_LD + e] = fmaf(nz, softplus_f(nl), route);
            }
    }
    __syncthreads();

    // ---- top-2 + softmax (one thread per token; in-order scan = stable ties) ----
    if (tid < M_TILE) {
        const int t = tid;
        float v1 = -INFINITY, v2 = -INFINITY;
        int e1 = 0, e2 = 0;
        #pragma unroll
        for (int e4 = 0; e4 < 16; ++e4) {
            float4 q = *(const float4*)&Cs[t * CS_LD + e4 * 4];
            float qa[4] = {q.x, q.y, q.z, q.w};
            #pragma unroll
            for (int c = 0; c < 4; ++c) {
                float v = qa[c];
                int e = e4 * 4 + c;
                if (v > v1) { v2 = v1; e2 = e1; v1 = v; e1 = e; }
                else if (v > v2) { v2 = v; e2 = e; }
            }
        }
        float ex = expf(v2 - v1);
        float denom = 1.f + ex;
        s_p1[t] = 1.f / denom;
        s_p2[t] = ex / denom;
        s_e1[t] = e1;
        s_e2[t] = e2;
        float2 iv = make_float2((float)e1, (float)e2);
        *(float2*)(out + OUT_IDX_BASE + (size_t)(m0 + t) * 2) = iv;
    }
    __syncthreads();

    // ---- coalesced scatter of router_output [32 tokens x 64 experts] ----
    #pragma unroll
    for (int i = 0; i < 2; ++i) {
        int gi = i * 256 + tid;       // 0..511 float4s
        int t  = gi >> 4;
        int e0 = (gi & 15) * 4;
        float p1 = s_p1[t], p2 = s_p2[t];
        int   e1 = s_e1[t], e2 = s_e2[t];
        float4 v;
        v.x = (e0 + 0 == e1) ? p1 : ((e0 + 0 == e2) ? p2 : 0.f);
        v.y = (e0 + 1 == e1) ? p1 : ((e0 + 1 == e2) ? p2 : 0.f);
        v.z = (e0 + 2 == e1) ? p1 : ((e0 + 2 == e2) ? p2 : 0.f);
        v.w = (e0 + 3 == e1) ? p1 : ((e0 + 3 == e2) ? p2 : 0.f);
        *(float4*)(out + (size_t)(m0 + t) * NE + e0) = v;
    }
}

extern "C" void kernel_launch(void* const* d_in, const int* in_sizes, int n_in,
                              void* d_out, int out_size, void* d_ws, size_t ws_size,
                              hipStream_t stream) {
    const float* A     = (const float*)d_in[0];
    const float* noise = (const float*)d_in[1];
    const float* Wr    = (const float*)d_in[2];
    const float* br    = (const float*)d_in[3];
    const float* Wn    = (const float*)d_in[4];
    const float* bn    = (const float*)d_in[5];
    float* out = (float*)d_out;

    short* Bh = (short*)d_ws;
    short* Bl = Bh + W_ELEMS;

    prepack_w<<<dim3(W_ELEMS / 8 / 256), dim3(256), 0, stream>>>(Wr, Wn, Bh, Bl);
    router_mfma<<<dim3(T_TOKENS / M_TILE), dim3(256), 0, stream>>>(A, noise, br, bn, Bh, Bl, out);
}